// Round 13
// baseline (108.044 us; speedup 1.0000x reference)
//
#include <hip/hip_runtime.h>

#ifndef __has_builtin
#define __has_builtin(x) 0
#endif
#if __has_builtin(__builtin_amdgcn_fdot2)
#define HAVE_FDOT2 1
#else
#define HAVE_FDOT2 0
#endif

typedef _Float16 f16;
typedef _Float16 f16x2 __attribute__((ext_vector_type(2)));
typedef _Float16 f16x8 __attribute__((ext_vector_type(8)));
typedef float    f32x4 __attribute__((ext_vector_type(4)));
typedef float    f32x2 __attribute__((ext_vector_type(2)));
typedef unsigned int u32x4 __attribute__((ext_vector_type(4)));

#define Bn 16
#define Cn 256
#define Hn 48
#define Wn 64
#define NDISP 21
#define SLAB 32768                      // bytes per (b,row) slab of in2, f16
#define WS_NEED ((size_t)Bn * Hn * SLAB)   // 25.2 MB

// ============================================================================
// Conversion kernel (in2 only), VERIFIED R5-R12: f32 [b][c][row][w] -> f16 ws
// slabs in MFMA-B-FRAGMENT order:
//   slab(b,row) offset = kc*8192 + par*4096 + ni*2048 + kk*1024 + g*256 + nl*16 + j*2
//   holds in2[b][c = kc*64 + kk*32 + g*8 + j][row][w = 2*(ni*16+nl) + par]
// ============================================================================
__global__ __launch_bounds__(256) void convert_kernel(const float* __restrict__ in2,
                                                      char* __restrict__ ws)
{
    int i = blockIdx.x;                         // 0..767
    int b = i / Hn, row = i % Hn;
    char* dslab = ws + (size_t)i * SLAB;
    int t  = threadIdx.x;
    int nl = t & 15, g = (t >> 4) & 3, kk = (t >> 6) & 1, ni = (t >> 7) & 1;
    int wq = ni * 16 + nl;                      // w' 0..31
    const float* srcb = in2 + ((size_t)b * Cn * Hn + row) * Wn;
    char* dbase = dslab + ni * 2048 + kk * 1024 + g * 256 + nl * 16;
    #pragma unroll
    for (int kc = 0; kc < 4; ++kc) {
        union { f16 h[8]; u32x4 u; } e0, e1;
        #pragma unroll
        for (int j = 0; j < 8; ++j) {
            int c = kc * 64 + kk * 32 + g * 8 + j;
            f32x2 v = *(const f32x2*)&srcb[(size_t)c * Hn * Wn + 2 * wq];
            e0.h[j] = (f16)v.x;                 // even w  (par 0)
            e1.h[j] = (f16)v.y;                 // odd  w  (par 1)
        }
        *(u32x4*)(dbase + kc * 8192)        = e0.u;
        *(u32x4*)(dbase + kc * 8192 + 4096) = e1.u;
    }
}

// ============================================================================
// Main kernel V13 = V12's barrier-free skeleton with the wave axis flipped
// from m-half to w-PARITY. V12's two half-waves loaded byte-identical B
// fragments (2x L2 waste); a parity wave owns a disjoint 16KB slab half:
// per k8 only 2 B-loads (ni0/ni1) feed 4 MFMAs -> B L2 traffic halves.
// Wave = (dy-slot, p2): full 32x32 one-parity gram, af[mi][k8] 64 VGPR,
// acc[mi][ni] 32 VGPR (same register shape as passing R12 -> no spill).
// No barriers, no global_load_lds, no asm waitcnt.
// ============================================================================
template<int NG>
__device__ void corr_wave(const char* __restrict__ wsb,
                          float* __restrict__ outb,
                          const f16x8 (&af)[2][8],
                          float* bp,
                          int h, int dylo, int slot, int p2, int l)
{
    const int nl  = l & 15;
    const int g   = l >> 4;
    const int l16 = l * 16;

    const char* gs[NG];
    #pragma unroll
    for (int gi = 0; gi < NG; ++gi) {
        int dy = dylo + slot + 8 * gi;
        int r  = h + 2 * dy - 20;               // in [0,48) by construction
        gs[gi] = wsb + (size_t)r * SLAB + p2 * 4096;   // this parity's slab half
    }

    #pragma unroll
    for (int gi = 0; gi < NG; ++gi) {
        const int dy = dylo + slot + 8 * gi;

        f32x4 acc[2][2];                        // [mi][ni]
        acc[0][0] = acc[0][1] = acc[1][0] = acc[1][1] = (f32x4){0.f, 0.f, 0.f, 0.f};

        #pragma unroll
        for (int k8 = 0; k8 < 8; ++k8) {
            const char* kb = gs[gi] + (k8 >> 1) * 8192 + (k8 & 1) * 1024 + l16;
            f16x8 b0 = *(const f16x8*)(kb);                 // ni = 0
            f16x8 b1 = *(const f16x8*)(kb + 2048);          // ni = 1
            acc[0][0] = __builtin_amdgcn_mfma_f32_16x16x32_f16(af[0][k8], b0, acc[0][0], 0, 0, 0);
            acc[0][1] = __builtin_amdgcn_mfma_f32_16x16x32_f16(af[0][k8], b1, acc[0][1], 0, 0, 0);
            acc[1][0] = __builtin_amdgcn_mfma_f32_16x16x32_f16(af[1][k8], b0, acc[1][0], 0, 0, 0);
            acc[1][1] = __builtin_amdgcn_mfma_f32_16x16x32_f16(af[1][k8], b1, acc[1][1], 0, 0, 0);
        }

        // ---- extraction via private bounce [21 dx][32 m], XOR-swizzled.
        // D layout (verified): col n = ni*16+nl, row m = mi*16 + 4g + rr.
        // o = n - m = dx-10; out w = 2m + p2.
        #pragma unroll
        for (int it = 0; it < 11; ++it) {
            int j = it * 64 + l;
            if (j < 672) bp[j] = 0.f;
        }
        asm volatile("" ::: "memory");
        #pragma unroll
        for (int mi = 0; mi < 2; ++mi)
            #pragma unroll
            for (int ni = 0; ni < 2; ++ni)
                #pragma unroll
                for (int rr = 0; rr < 4; ++rr) {
                    int o = nl + 16 * (ni - mi) - 4 * g - rr;   // dx - 10
                    if (o >= -10 && o <= 10) {
                        int dx = o + 10;
                        int m  = mi * 16 + 4 * g + rr;          // 0..31
                        bp[dx * 32 + (m ^ ((dx & 7) << 2))] = acc[mi][ni][rr];
                    }
                }
        asm volatile("" ::: "memory");
        // ---- gather + stride-2 scalar stores (w = 2m+p2); the sibling
        // parity wave fills the holes -> L2 write-combines to full lines.
        #pragma unroll
        for (int it = 0; it < 11; ++it) {
            int j = it * 64 + l;
            if (j < 672) {
                int dx = j >> 5;
                int m  = (j & 31) ^ ((dx & 7) << 2);
                int w  = 2 * m + p2;
                outb[((size_t)(dy * NDISP + dx) * Hn + h) * Wn + w] =
                    bp[j] * (1.0f / 256.0f);
            }
        }
        asm volatile("" ::: "memory");          // bounce reused by next gram
    }
}

__global__ __launch_bounds__(512, 2) void corr_mfma(const float* __restrict__ in1,
                                                    const char* __restrict__ ws,
                                                    float* __restrict__ out)
{
    __shared__ float bounce[8][672];            // 21.5 KB, per-wave private

    const int tid = threadIdx.x;
    const int wv  = tid >> 6;                   // 0..7
    const int l   = tid & 63;
    const int nl  = l & 15;
    const int g   = l >> 4;
    const int p2  = wv & 1;                     // w parity

    // XCD-affine bijective mapping over 1536 = 8 xcd * 2 b * 48 h * 2 sub:
    // xcd owns b in {2*xcd, 2*xcd+1} -> per-XCD ws slice 3.15 MB (L2-fit).
    int bid = blockIdx.x;
    int rr  = bid >> 3;                         // 0..191
    int b   = 2 * (bid & 7) + (rr >= 96 ? 1 : 0);
    int q   = (rr >= 96) ? (rr - 96) : rr;      // 0..95
    int h   = q >> 1;
    int sub = q & 1;
    const int slot = 4 * sub + (wv >> 1);       // dy slot 0..7

    const float* in1b = in1 + (size_t)b * Cn * Hn * Wn;
    const char*  wsb  = ws  + (size_t)b * Hn * SLAB;
    float* outb = out + (size_t)b * (NDISP * NDISP) * Hn * Wn;

    int dylo = (h < 20) ? ((21 - h) >> 1) : 0;
    int dyhi = min(NDISP, ((67 - h) >> 1) + 1);
    int V    = dyhi - dylo;                     // 11..21 (every slot has >=1)

    // ---- zero invalid-dy planes, split across the two sibling blocks ----
    {
        int nz = NDISP - V;
        f32x4 z = {0.f, 0.f, 0.f, 0.f};
        for (int zi = sub; zi < nz; zi += 2) {
            int dy = (zi < dylo) ? zi : (dyhi + (zi - dylo));
            for (int j = tid; j < NDISP * 16; j += 512) {
                int dx = j >> 4;
                int wq = j & 15;
                *(f32x4*)&outb[((size_t)(dy * NDISP + dx) * Hn + h) * Wn + wq * 4] = z;
            }
        }
    }

    // ---- A-fragments (VERIFIED contract): af[mi][k8] elem j =
    //      f16(in1[c=k8*32+g*8+j][h][w=2*(mi*16+nl)+p2]) ----
    f16x8 af[2][8];
    #pragma unroll
    for (int mi = 0; mi < 2; ++mi) {
        const int w2 = 2 * (mi * 16 + nl);
        #pragma unroll
        for (int k8 = 0; k8 < 8; ++k8)
            #pragma unroll
            for (int j = 0; j < 8; ++j) {
                int c = k8 * 32 + g * 8 + j;
                f32x2 v = *(const f32x2*)&in1b[((size_t)c * Hn + h) * Wn + w2];
                af[mi][k8][j] = (f16)(p2 ? v.y : v.x);
            }
    }

    int ng = (V - slot + 7) >> 3;               // 1..3 (V>=11 > slot max 7)
    float* bp = &bounce[wv][0];

    if (ng >= 3)      corr_wave<3>(wsb, outb, af, bp, h, dylo, slot, p2, l);
    else if (ng == 2) corr_wave<2>(wsb, outb, af, bp, h, dylo, slot, p2, l);
    else              corr_wave<1>(wsb, outb, af, bp, h, dylo, slot, p2, l);
}

// ============================================================================
// Fallback (round-1 kernel, known-good) if ws_size is too small.
// ============================================================================
#define BDIM 384
#define C2T  8
#define NCHUNK 16
#define JJN  56
#define IN1_DW (2*128*32)
#define IN2_DW (128*JJN + 64)

__device__ __forceinline__ unsigned int packh2(float a, float b) {
    union { f16x2 h; unsigned int u; } u;
    u.h.x = (_Float16)a; u.h.y = (_Float16)b;
    return u.u;
}
__device__ __forceinline__ float dot2(unsigned int a, unsigned int b, float c) {
    union { unsigned int u; f16x2 h; } ua, ub;
    ua.u = a; ub.u = b;
#if HAVE_FDOT2
    return __builtin_amdgcn_fdot2(ua.h, ub.h, c, false);
#else
    return c + (float)ua.h.x * (float)ub.h.x + (float)ua.h.y * (float)ub.h.y;
#endif
}
__device__ __forceinline__ int in2row(int m) { return m * JJN + (((m >> 3) & 1) << 2); }

__global__ __launch_bounds__(BDIM, 3) void corr_fallback(
    const float* __restrict__ in1, const float* __restrict__ in2,
    float* __restrict__ out)
{
    __shared__ __align__(16) unsigned int s_in1[IN1_DW];
    __shared__ __align__(16) unsigned int s_in2[IN2_DW];
    const int tid = threadIdx.x;
    int bid = blockIdx.x;
    int sw  = (bid & 7) * 96 + (bid >> 3);
    const int b = sw / Hn;
    const int h = sw - b * Hn;
    int dylo = (h < 20) ? ((21 - h) >> 1) : 0;
    int dyhi = min(NDISP - 1, (67 - h) >> 1) + 1;
    const int V = dyhi - dylo;
    const int wg   = tid & 15;
    const int p    = wg & 1;
    const int widx = (wg >> 1) << 2;
    const int t2   = tid >> 4;
    const int dxg  = t2 % 3;
    const int slot = t2 / 3;
    const int dxb  = dxg << 3;
    const float* in1b = in1 + (size_t)b * Cn * Hn * Wn;
    const float* in2b = in2 + (size_t)b * Cn * Hn * Wn;
    float* outb = out + (size_t)b * (NDISP * NDISP) * Hn * Wn;
    {
        int nz = NDISP - V;
        for (int j = tid; j < nz * NDISP * Wn; j += BDIM) {
            int zi  = j / (NDISP * Wn);
            int rem = j - zi * (NDISP * Wn);
            int dy  = (zi < dylo) ? zi : (dyhi + (zi - dylo));
            int dx  = rem >> 6;
            int w   = rem & 63;
            outb[((size_t)(dy * NDISP + dx) * Hn + h) * Wn + w] = 0.0f;
        }
    }
    for (int i = tid; i < 64 * 128; i += BDIM) {
        int w  = i & 63;
        int c2 = i >> 6;
        float f0 = in1b[((size_t)(2 * c2)     * Hn + h) * Wn + w];
        float f1 = in1b[((size_t)(2 * c2 + 1) * Hn + h) * Wn + w];
        int pp = w & 1, wq = w >> 1;
        s_in1[(pp * 128 + c2) * 32 + wq] = packh2(f0, f1);
    }
    const int nR = (V + 7) >> 3;
    for (int round = 0; round < nR; ++round) {
        const int dy0   = dylo + (round << 3);
        const int mydy  = dy0 + slot;
        const bool valid = (mydy < dyhi);
        float acc[4][8];
        #pragma unroll
        for (int i = 0; i < 4; ++i)
            #pragma unroll
            for (int j = 0; j < 8; ++j) acc[i][j] = 0.0f;
        for (int ch = 0; ch < NCHUNK; ++ch) {
            const int c2b = ch * C2T;
            __syncthreads();
            for (int i = tid; i < 8 * 2 * C2T * 112 / 2; i += BDIM) {
                int jj2 = i % 112;
                int t   = i / 112;
                int pp  = jj2 & 1;
                int jj  = jj2 >> 1;
                int c2o = t % C2T;
                int sl  = t / C2T;
                int dy  = dy0 + sl;
                if (dy >= dyhi) continue;
                int w2  = jj2 - 20;
                unsigned int val = 0;
                if (w2 >= 0 && w2 < Wn) {
                    int rr = h + 2 * dy - 20;
                    int c = 2 * (c2b + c2o);
                    const float* srcp = &in2b[((size_t)c * Hn + rr) * Wn + w2];
                    val = packh2(srcp[0], srcp[Hn * Wn]);
                }
                s_in2[in2row((sl * 2 + pp) * C2T + c2o) + jj] = val;
            }
            __syncthreads();
            if (valid) {
                const int base1 = (p * 128 + c2b) * 32 + widx;
                #pragma unroll
                for (int c2o = 0; c2o < C2T; ++c2o) {
                    u32x4 a4 = *(const u32x4*)&s_in1[base1 + c2o * 32];
                    const unsigned int* vr =
                        &s_in2[in2row((slot * 2 + p) * C2T + c2o) + widx + dxb];
                    u32x4 v0 = *(const u32x4*)(vr);
                    u32x4 v1 = *(const u32x4*)(vr + 4);
                    u32x4 v2 = *(const u32x4*)(vr + 8);
                    unsigned int av[4]  = {a4.x, a4.y, a4.z, a4.w};
                    unsigned int vv[12] = {v0.x, v0.y, v0.z, v0.w,
                                           v1.x, v1.y, v1.z, v1.w,
                                           v2.x, v2.y, v2.z, v2.w};
                    #pragma unroll
                    for (int wi = 0; wi < 4; ++wi)
                        #pragma unroll
                        for (int di = 0; di < 8; ++di)
                            acc[wi][di] = dot2(av[wi], vv[wi + di], acc[wi][di]);
                }
            }
        }
        float* s_out = (float*)s_in2;
        for (int half = 0; half < 2; ++half) {
            __syncthreads();
            if (((slot >> 2) == half) && valid) {
                #pragma unroll
                for (int wi = 0; wi < 4; ++wi)
                    #pragma unroll
                    for (int di = 0; di < 8; ++di) {
                        int dx = dxb + di;
                        if (dx < NDISP) {
                            int w = p + ((widx + wi) << 1);
                            s_out[(((slot & 3) * NDISP + dx) << 6) + w] =
                                acc[wi][di] * (1.0f / 256.0f);
                        }
                    }
            }
            __syncthreads();
            int dyb = dy0 + (half << 2);
            for (int j = tid; j < 4 * NDISP * Wn; j += BDIM) {
                int s  = j / (NDISP * Wn);
                int dy = dyb + s;
                if (dy < dyhi) {
                    int rem = j - s * (NDISP * Wn);
                    int dx  = rem >> 6;
                    int w   = rem & 63;
                    outb[((size_t)(dy * NDISP + dx) * Hn + h) * Wn + w] = s_out[j];
                }
            }
        }
    }
}

extern "C" void kernel_launch(void* const* d_in, const int* in_sizes, int n_in,
                              void* d_out, int out_size, void* d_ws, size_t ws_size,
                              hipStream_t stream) {
    (void)in_sizes; (void)n_in; (void)out_size;
    const float* in1 = (const float*)d_in[0];
    const float* in2 = (const float*)d_in[1];
    float* out = (float*)d_out;
    if (ws_size >= WS_NEED) {
        convert_kernel<<<dim3(Bn * Hn), dim3(256), 0, stream>>>(in2, (char*)d_ws);
        corr_mfma<<<dim3(2 * Bn * Hn), dim3(512), 0, stream>>>(in1, (const char*)d_ws, out);
    } else {
        corr_fallback<<<dim3(Bn * Hn), dim3(BDIM), 0, stream>>>(in1, in2, out);
    }
}

// Round 14
// 94.952 us; speedup vs baseline: 1.1379x; 1.1379x over previous
//
#include <hip/hip_runtime.h>

#ifndef __has_builtin
#define __has_builtin(x) 0
#endif
#if __has_builtin(__builtin_amdgcn_fdot2)
#define HAVE_FDOT2 1
#else
#define HAVE_FDOT2 0
#endif

#define AS1q __attribute__((address_space(1)))
#define AS3q __attribute__((address_space(3)))

typedef _Float16 f16;
typedef _Float16 f16x2 __attribute__((ext_vector_type(2)));
typedef _Float16 f16x8 __attribute__((ext_vector_type(8)));
typedef float    f32x4 __attribute__((ext_vector_type(4)));
typedef float    f32x2 __attribute__((ext_vector_type(2)));
typedef unsigned int u32x4 __attribute__((ext_vector_type(4)));

#define Bn 16
#define Cn 256
#define Hn 48
#define Wn 64
#define NDISP 21
#define SLAB 32768                      // bytes per (b,row) slab of in2, f16
#define WS_NEED ((size_t)Bn * Hn * SLAB)   // 25.2 MB

// ============================================================================
// Conversion kernel (in2 only), VERIFIED R5-R13: f32 [b][c][row][w] -> f16 ws
// slabs in MFMA-B-FRAGMENT order:
//   slab(b,row) offset = kc*8192 + par*4096 + ni*2048 + kk*1024 + g*256 + nl*16 + j*2
//   holds in2[b][c = kc*64 + kk*32 + g*8 + j][row][w = 2*(ni*16+nl) + par]
// ============================================================================
__global__ __launch_bounds__(256) void convert_kernel(const float* __restrict__ in2,
                                                      char* __restrict__ ws)
{
    int i = blockIdx.x;                         // 0..767
    int b = i / Hn, row = i % Hn;
    char* dslab = ws + (size_t)i * SLAB;
    int t  = threadIdx.x;
    int nl = t & 15, g = (t >> 4) & 3, kk = (t >> 6) & 1, ni = (t >> 7) & 1;
    int wq = ni * 16 + nl;                      // w' 0..31
    const float* srcb = in2 + ((size_t)b * Cn * Hn + row) * Wn;
    char* dbase = dslab + ni * 2048 + kk * 1024 + g * 256 + nl * 16;
    #pragma unroll
    for (int kc = 0; kc < 4; ++kc) {
        union { f16 h[8]; u32x4 u; } e0, e1;
        #pragma unroll
        for (int j = 0; j < 8; ++j) {
            int c = kc * 64 + kk * 32 + g * 8 + j;
            f32x2 v = *(const f32x2*)&srcb[(size_t)c * Hn * Wn + 2 * wq];
            e0.h[j] = (f16)v.x;                 // even w  (par 0)
            e1.h[j] = (f16)v.y;                 // odd  w  (par 1)
        }
        *(u32x4*)(dbase + kc * 8192)        = e0.u;
        *(u32x4*)(dbase + kc * 8192 + 4096) = e1.u;
    }
}

// ============================================================================
// Main kernel V14: R7/R10's verified engine at full occupancy.
// Block = (b, h-parity pi, 2-h tile, row-half): 768 blocks, 512 thr, 8 waves
// = (plane i x m-half x w-parity p2). Per step: one in2 row slab (32KB, both
// w-parities) staged once into a 2-slot LDS ring; each wave computes its
// quarter of up to 2 (h,dy) parity-grams: af[8] in regs (once per block),
// 16 ds_read_b128 + 16 MFMA; scatter into pair-shared XOR-swizzled bounce;
// full f32x4 coalesced stores. Counted vmcnt(4)+raw-barrier sync (R10 pattern).
// LDS 76.3KB -> 2 blocks/CU = 4 waves/SIMD; grid 768 = 3 blocks/CU (no idle CUs).
// ============================================================================
__global__ __launch_bounds__(512, 4) void corr_mfma(const float* __restrict__ in1,
                                                    const char* __restrict__ ws,
                                                    float* __restrict__ out)
{
    __shared__ char  ring[2][32768];            // 64 KB row-slab double buffer
    __shared__ float bounce[2][1344];           // per-plane [21 dx][64 w] (10.75 KB)

    const int tid  = threadIdx.x;
    const int wv   = tid >> 6;                  // 0..7
    const int l    = tid & 63;
    const int nl   = l & 15;
    const int g    = l >> 4;                    // 0..3
    const int i    = wv >> 2;                   // plane (h index) 0..1
    const int half = (wv >> 1) & 1;             // m-half
    const int p2   = wv & 1;                    // w parity

    // XCD-affine bijective mapping over 768 = 8 xcd * 2 b * 48 inner:
    int bid   = blockIdx.x;
    int rr    = bid >> 3;                       // 0..95
    int b     = 2 * (bid & 7) + (rr >= 48 ? 1 : 0);
    int inner = (rr >= 48) ? (rr - 48) : rr;    // 0..47
    int rh    = inner & 1;                      // row-half
    int pi    = (inner >> 1) & 1;               // h parity
    int t     = inner >> 2;                     // 0..11
    int h0    = pi + 4 * t;                     // tile h's: h0, h0+2
    const int h_i = h0 + 2 * i;                 // this wave's h

    const float* in1b = in1 + (size_t)b * Cn * Hn * Wn;
    const char*  wsb  = ws  + (size_t)b * Hn * SLAB;
    float* outb = out + (size_t)b * (NDISP * NDISP) * Hn * Wn;

    // rows r = h + 2dy - 20 for h in {h0, h0+2}: r in [h0-20, h0+22], parity pi
    int rlo = h0 - 20; if (rlo < 0) rlo = pi;
    int rhi = h0 + 22; if (rhi > 47) rhi = 46 + pi;
    int NR  = ((rhi - rlo) >> 1) + 1;           // 12..22
    int NH  = (NR + 1) >> 1;
    int s0  = rh ? NH : 0;
    int s1  = rh ? NR : NH;

    // ---- zero invalid-dy planes (rh==0 blocks only; both h's of the tile) ----
    if (rh == 0) {
        f32x4 z = {0.f, 0.f, 0.f, 0.f};
        #pragma unroll
        for (int ii = 0; ii < 2; ++ii) {
            int h = h0 + 2 * ii;
            int dylo = (h < 20) ? ((21 - h) >> 1) : 0;
            int dyhi = min(NDISP, ((67 - h) >> 1) + 1);
            int nz = NDISP - (dyhi - dylo);
            for (int j = tid; j < nz * NDISP * 16; j += 512) {
                int zi  = j / (NDISP * 16);
                int rem = j - zi * (NDISP * 16);
                int dy  = (zi < dylo) ? zi : (dyhi + (zi - dylo));
                int dx  = rem >> 4;
                int wq  = rem & 15;
                *(f32x4*)&outb[((size_t)(dy * NDISP + dx) * Hn + h) * Wn + wq * 4] = z;
            }
        }
    }

    // ---- A-fragments (VERIFIED contract): af[k8] elem j =
    //      f16(in1[c=k8*32+g*8+j][h_i][w=2*(half*16+nl)+p2]) ----
    f16x8 af[8];
    {
        const int w2 = 2 * (half * 16 + nl);
        #pragma unroll
        for (int k8 = 0; k8 < 8; ++k8)
            #pragma unroll
            for (int j = 0; j < 8; ++j) {
                int c = k8 * 32 + g * 8 + j;
                f32x2 v = *(const f32x2*)&in1b[((size_t)c * Hn + h_i) * Wn + w2];
                af[k8][j] = (f16)(p2 ? v.y : v.x);
            }
    }

    // ---- zero bounce planes ----
    for (int j = tid; j < 2 * 1344; j += 512) (&bounce[0][0])[j] = 0.f;

    const int soff = wv * 4096;                 // this wave's 4KB staging share
    const int l16  = l * 16;

    // ---- prologue: stage row s0 into slot s0&1 ----
    {
        const char* slab = wsb + (size_t)(rlo + 2 * s0) * SLAB;
        char* dst = &ring[s0 & 1][0];
        #pragma unroll
        for (int q = 0; q < 4; ++q) {
            int off = soff + q * 1024 + l16;
            __builtin_amdgcn_global_load_lds((const AS1q void*)(slab + off),
                                             (AS3q void*)(dst + off), 16, 0, 0);
        }
    }

    for (int s = s0; s < s1; ++s) {
        // stage row s+1 (clamped dummy at tail; target slot never read then)
        {
            int sn = (s + 1 < s1) ? s + 1 : s1 - 1;
            const char* slab = wsb + (size_t)(rlo + 2 * sn) * SLAB;
            char* dst = &ring[(s + 1) & 1][0];
            #pragma unroll
            for (int q = 0; q < 4; ++q) {
                int off = soff + q * 1024 + l16;
                __builtin_amdgcn_global_load_lds((const AS1q void*)(slab + off),
                                                 (AS3q void*)(dst + off), 16, 0, 0);
            }
        }
        // barrier1: own stage(s) proven done (4 newer loads in flight; loads
        // retire in order, stores only inflate); bounce zeros/re-zeros visible.
        __builtin_amdgcn_sched_barrier(0);
        asm volatile("s_waitcnt vmcnt(4) lgkmcnt(0)" ::: "memory");
        __builtin_amdgcn_s_barrier();
        __builtin_amdgcn_sched_barrier(0);

        const int r  = rlo + 2 * s;
        const int dy = (r - h_i + 20) / 2;      // exact (even numerator)
        const bool valid = (dy >= 0) && (dy < NDISP);

        if (valid) {
            f32x4 acc[2];                       // [ni]
            acc[0] = acc[1] = (f32x4){0.f, 0.f, 0.f, 0.f};
            const char* base = &ring[s & 1][0] + p2 * 4096;
            #pragma unroll
            for (int k8 = 0; k8 < 8; ++k8) {
                const char* kb = base + (k8 >> 1) * 8192 + (k8 & 1) * 1024 + l16;
                f16x8 b0 = *(const f16x8*)(kb);           // ni = 0
                f16x8 b1 = *(const f16x8*)(kb + 2048);    // ni = 1
                acc[0] = __builtin_amdgcn_mfma_f32_16x16x32_f16(af[k8], b0, acc[0], 0, 0, 0);
                acc[1] = __builtin_amdgcn_mfma_f32_16x16x32_f16(af[k8], b1, acc[1], 0, 0, 0);
            }
            // scatter (VERIFIED o = n - m): n = ni*16+nl, m = half*16+4g+rr,
            // w = 2m+p2, swizzle w ^ ((dx&7)<<3)
            #pragma unroll
            for (int ni = 0; ni < 2; ++ni)
                #pragma unroll
                for (int rr2 = 0; rr2 < 4; ++rr2) {
                    int o = nl + 16 * ni - 16 * half - 4 * g - rr2;  // dx - 10
                    if (o >= -10 && o <= 10) {
                        int dx = o + 10;
                        int m  = half * 16 + 4 * g + rr2;
                        int w  = 2 * m + p2;
                        bounce[i][dx * 64 + (w ^ ((dx & 7) << 3))] = acc[ni][rr2];
                    }
                }
        }
        // barrier2: scatter visible to plane partners; ds_reads retired ->
        // ring slot s&1 free for stage(s+2).
        __builtin_amdgcn_sched_barrier(0);
        asm volatile("s_waitcnt lgkmcnt(0)" ::: "memory");
        __builtin_amdgcn_s_barrier();
        __builtin_amdgcn_sched_barrier(0);

        if (valid) {
            // gather + coalesced f32x4 stores + re-zero (336 = 21 dx x 16 quads
            // per plane; 4 waves of this plane cooperate)
            #pragma unroll
            for (int it = 0; it < 2; ++it) {
                int pos = it * 256 + (wv & 3) * 64 + l;
                if (pos < 336) {
                    int dx = pos >> 4;
                    int q  = pos & 15;
                    int idx = dx * 64 + ((4 * q) ^ ((dx & 7) << 3));
                    f32x4 v = *(f32x4*)&bounce[i][idx];
                    v = v * (1.0f / 256.0f);
                    *(f32x4*)&outb[((size_t)(dy * NDISP + dx) * Hn + h_i) * Wn + 4 * q] = v;
                    *(f32x4*)&bounce[i][idx] = (f32x4){0.f, 0.f, 0.f, 0.f};
                }
            }
        }
    }
}

// ============================================================================
// Fallback (round-1 kernel, known-good) if ws_size is too small.
// ============================================================================
#define BDIM 384
#define C2T  8
#define NCHUNK 16
#define JJN  56
#define IN1_DW (2*128*32)
#define IN2_DW (128*JJN + 64)

__device__ __forceinline__ unsigned int packh2(float a, float b) {
    union { f16x2 h; unsigned int u; } u;
    u.h.x = (_Float16)a; u.h.y = (_Float16)b;
    return u.u;
}
__device__ __forceinline__ float dot2(unsigned int a, unsigned int b, float c) {
    union { unsigned int u; f16x2 h; } ua, ub;
    ua.u = a; ub.u = b;
#if HAVE_FDOT2
    return __builtin_amdgcn_fdot2(ua.h, ub.h, c, false);
#else
    return c + (float)ua.h.x * (float)ub.h.x + (float)ua.h.y * (float)ub.h.y;
#endif
}
__device__ __forceinline__ int in2row(int m) { return m * JJN + (((m >> 3) & 1) << 2); }

__global__ __launch_bounds__(BDIM, 3) void corr_fallback(
    const float* __restrict__ in1, const float* __restrict__ in2,
    float* __restrict__ out)
{
    __shared__ __align__(16) unsigned int s_in1[IN1_DW];
    __shared__ __align__(16) unsigned int s_in2[IN2_DW];
    const int tid = threadIdx.x;
    int bid = blockIdx.x;
    int sw  = (bid & 7) * 96 + (bid >> 3);
    const int b = sw / Hn;
    const int h = sw - b * Hn;
    int dylo = (h < 20) ? ((21 - h) >> 1) : 0;
    int dyhi = min(NDISP - 1, (67 - h) >> 1) + 1;
    const int V = dyhi - dylo;
    const int wg   = tid & 15;
    const int p    = wg & 1;
    const int widx = (wg >> 1) << 2;
    const int t2   = tid >> 4;
    const int dxg  = t2 % 3;
    const int slot = t2 / 3;
    const int dxb  = dxg << 3;
    const float* in1b = in1 + (size_t)b * Cn * Hn * Wn;
    const float* in2b = in2 + (size_t)b * Cn * Hn * Wn;
    float* outb = out + (size_t)b * (NDISP * NDISP) * Hn * Wn;
    {
        int nz = NDISP - V;
        for (int j = tid; j < nz * NDISP * Wn; j += BDIM) {
            int zi  = j / (NDISP * Wn);
            int rem = j - zi * (NDISP * Wn);
            int dy  = (zi < dylo) ? zi : (dyhi + (zi - dylo));
            int dx  = rem >> 6;
            int w   = rem & 63;
            outb[((size_t)(dy * NDISP + dx) * Hn + h) * Wn + w] = 0.0f;
        }
    }
    for (int i = tid; i < 64 * 128; i += BDIM) {
        int w  = i & 63;
        int c2 = i >> 6;
        float f0 = in1b[((size_t)(2 * c2)     * Hn + h) * Wn + w];
        float f1 = in1b[((size_t)(2 * c2 + 1) * Hn + h) * Wn + w];
        int pp = w & 1, wq = w >> 1;
        s_in1[(pp * 128 + c2) * 32 + wq] = packh2(f0, f1);
    }
    const int nR = (V + 7) >> 3;
    for (int round = 0; round < nR; ++round) {
        const int dy0   = dylo + (round << 3);
        const int mydy  = dy0 + slot;
        const bool valid = (mydy < dyhi);
        float acc[4][8];
        #pragma unroll
        for (int i = 0; i < 4; ++i)
            #pragma unroll
            for (int j = 0; j < 8; ++j) acc[i][j] = 0.0f;
        for (int ch = 0; ch < NCHUNK; ++ch) {
            const int c2b = ch * C2T;
            __syncthreads();
            for (int i = tid; i < 8 * 2 * C2T * 112 / 2; i += BDIM) {
                int jj2 = i % 112;
                int t   = i / 112;
                int pp  = jj2 & 1;
                int jj  = jj2 >> 1;
                int c2o = t % C2T;
                int sl  = t / C2T;
                int dy  = dy0 + sl;
                if (dy >= dyhi) continue;
                int w2  = jj2 - 20;
                unsigned int val = 0;
                if (w2 >= 0 && w2 < Wn) {
                    int rr = h + 2 * dy - 20;
                    int c = 2 * (c2b + c2o);
                    const float* srcp = &in2b[((size_t)c * Hn + rr) * Wn + w2];
                    val = packh2(srcp[0], srcp[Hn * Wn]);
                }
                s_in2[in2row((sl * 2 + pp) * C2T + c2o) + jj] = val;
            }
            __syncthreads();
            if (valid) {
                const int base1 = (p * 128 + c2b) * 32 + widx;
                #pragma unroll
                for (int c2o = 0; c2o < C2T; ++c2o) {
                    u32x4 a4 = *(const u32x4*)&s_in1[base1 + c2o * 32];
                    const unsigned int* vr =
                        &s_in2[in2row((slot * 2 + p) * C2T + c2o) + widx + dxb];
                    u32x4 v0 = *(const u32x4*)(vr);
                    u32x4 v1 = *(const u32x4*)(vr + 4);
                    u32x4 v2 = *(const u32x4*)(vr + 8);
                    unsigned int av[4]  = {a4.x, a4.y, a4.z, a4.w};
                    unsigned int vv[12] = {v0.x, v0.y, v0.z, v0.w,
                                           v1.x, v1.y, v1.z, v1.w,
                                           v2.x, v2.y, v2.z, v2.w};
                    #pragma unroll
                    for (int wi = 0; wi < 4; ++wi)
                        #pragma unroll
                        for (int di = 0; di < 8; ++di)
                            acc[wi][di] = dot2(av[wi], vv[wi + di], acc[wi][di]);
                }
            }
        }
        float* s_out = (float*)s_in2;
        for (int half = 0; half < 2; ++half) {
            __syncthreads();
            if (((slot >> 2) == half) && valid) {
                #pragma unroll
                for (int wi = 0; wi < 4; ++wi)
                    #pragma unroll
                    for (int di = 0; di < 8; ++di) {
                        int dx = dxb + di;
                        if (dx < NDISP) {
                            int w = p + ((widx + wi) << 1);
                            s_out[(((slot & 3) * NDISP + dx) << 6) + w] =
                                acc[wi][di] * (1.0f / 256.0f);
                        }
                    }
            }
            __syncthreads();
            int dyb = dy0 + (half << 2);
            for (int j = tid; j < 4 * NDISP * Wn; j += BDIM) {
                int s  = j / (NDISP * Wn);
                int dy = dyb + s;
                if (dy < dyhi) {
                    int rem = j - s * (NDISP * Wn);
                    int dx  = rem >> 6;
                    int w   = rem & 63;
                    outb[((size_t)(dy * NDISP + dx) * Hn + h) * Wn + w] = s_out[j];
                }
            }
        }
    }
}

extern "C" void kernel_launch(void* const* d_in, const int* in_sizes, int n_in,
                              void* d_out, int out_size, void* d_ws, size_t ws_size,
                              hipStream_t stream) {
    (void)in_sizes; (void)n_in; (void)out_size;
    const float* in1 = (const float*)d_in[0];
    const float* in2 = (const float*)d_in[1];
    float* out = (float*)d_out;
    if (ws_size >= WS_NEED) {
        convert_kernel<<<dim3(Bn * Hn), dim3(256), 0, stream>>>(in2, (char*)d_ws);
        corr_mfma<<<dim3(768), dim3(512), 0, stream>>>(in1, (const char*)d_ws, out);
    } else {
        corr_fallback<<<dim3(Bn * Hn), dim3(BDIM), 0, stream>>>(in1, in2, out);
    }
}

// Round 15
// 66.496 us; speedup vs baseline: 1.6248x; 1.4279x over previous
//
#include <hip/hip_runtime.h>

#ifndef __has_builtin
#define __has_builtin(x) 0
#endif
#if __has_builtin(__builtin_amdgcn_fdot2)
#define HAVE_FDOT2 1
#else
#define HAVE_FDOT2 0
#endif

#define AS1q __attribute__((address_space(1)))
#define AS3q __attribute__((address_space(3)))

typedef _Float16 f16;
typedef _Float16 f16x2 __attribute__((ext_vector_type(2)));
typedef _Float16 f16x8 __attribute__((ext_vector_type(8)));
typedef float    f32x4 __attribute__((ext_vector_type(4)));
typedef float    f32x2 __attribute__((ext_vector_type(2)));
typedef unsigned int u32x4 __attribute__((ext_vector_type(4)));

#define Bn 16
#define Cn 256
#define Hn 48
#define Wn 64
#define NDISP 21
#define SLAB 32768                      // bytes per (b,row) slab of in2, f16
#define WS_NEED ((size_t)Bn * Hn * SLAB)   // 25.2 MB

// ============================================================================
// Conversion kernel (in2 only), VERIFIED R5-R14: f32 [b][c][row][w] -> f16 ws
// slabs in MFMA-B-FRAGMENT order:
//   slab(b,row) offset = kc*8192 + par*4096 + ni*2048 + kk*1024 + g*256 + nl*16 + j*2
//   holds in2[b][c = kc*64 + kk*32 + g*8 + j][row][w = 2*(ni*16+nl) + par]
// ============================================================================
__global__ __launch_bounds__(256) void convert_kernel(const float* __restrict__ in2,
                                                      char* __restrict__ ws)
{
    int i = blockIdx.x;                         // 0..767
    int b = i / Hn, row = i % Hn;
    char* dslab = ws + (size_t)i * SLAB;
    int t  = threadIdx.x;
    int nl = t & 15, g = (t >> 4) & 3, kk = (t >> 6) & 1, ni = (t >> 7) & 1;
    int wq = ni * 16 + nl;                      // w' 0..31
    const float* srcb = in2 + ((size_t)b * Cn * Hn + row) * Wn;
    char* dbase = dslab + ni * 2048 + kk * 1024 + g * 256 + nl * 16;
    #pragma unroll
    for (int kc = 0; kc < 4; ++kc) {
        union { f16 h[8]; u32x4 u; } e0, e1;
        #pragma unroll
        for (int j = 0; j < 8; ++j) {
            int c = kc * 64 + kk * 32 + g * 8 + j;
            f32x2 v = *(const f32x2*)&srcb[(size_t)c * Hn * Wn + 2 * wq];
            e0.h[j] = (f16)v.x;                 // even w  (par 0)
            e1.h[j] = (f16)v.y;                 // odd  w  (par 1)
        }
        *(u32x4*)(dbase + kc * 8192)        = e0.u;
        *(u32x4*)(dbase + kc * 8192 + 4096) = e1.u;
    }
}

// ============================================================================
// Main kernel V15 = V14 (passed correctness) with __launch_bounds__(512,2):
// the (512,4) bound empirically pins hipcc's allocator at 64 VGPR -> spill
// (R6/R11/R14 all show VGPR=64 + ~72MB scratch writes); (512,2) allocates
// honestly (R10: 88, R12: 84). The 76.3 KB LDS already enforces 2 blocks/CU
// = 4 waves/SIMD, which is the occupancy the aggressive bound was meant for.
//
// Block = (b, h-parity pi, 2-h tile, row-half): 768 blocks, 512 thr, 8 waves
// = (plane i x m-half x w-parity p2). Per step: one in2 row slab (32KB, both
// w-parities) staged once into a 2-slot LDS ring; each wave computes its
// quarter of up to 2 (h,dy) parity-grams: af[8] in regs (once per block),
// 16 ds_read_b128 + 16 MFMA; scatter into pair-shared XOR-swizzled bounce;
// full f32x4 coalesced stores. Counted vmcnt(4)+raw-barrier sync (R10 pattern).
// ============================================================================
__global__ __launch_bounds__(512, 2) void corr_mfma(const float* __restrict__ in1,
                                                    const char* __restrict__ ws,
                                                    float* __restrict__ out)
{
    __shared__ char  ring[2][32768];            // 64 KB row-slab double buffer
    __shared__ float bounce[2][1344];           // per-plane [21 dx][64 w] (10.75 KB)

    const int tid  = threadIdx.x;
    const int wv   = tid >> 6;                  // 0..7
    const int l    = tid & 63;
    const int nl   = l & 15;
    const int g    = l >> 4;                    // 0..3
    const int i    = wv >> 2;                   // plane (h index) 0..1
    const int half = (wv >> 1) & 1;             // m-half
    const int p2   = wv & 1;                    // w parity

    // XCD-affine bijective mapping over 768 = 8 xcd * 2 b * 48 inner:
    int bid   = blockIdx.x;
    int rr    = bid >> 3;                       // 0..95
    int b     = 2 * (bid & 7) + (rr >= 48 ? 1 : 0);
    int inner = (rr >= 48) ? (rr - 48) : rr;    // 0..47
    int rh    = inner & 1;                      // row-half
    int pi    = (inner >> 1) & 1;               // h parity
    int t     = inner >> 2;                     // 0..11
    int h0    = pi + 4 * t;                     // tile h's: h0, h0+2
    const int h_i = h0 + 2 * i;                 // this wave's h

    const float* in1b = in1 + (size_t)b * Cn * Hn * Wn;
    const char*  wsb  = ws  + (size_t)b * Hn * SLAB;
    float* outb = out + (size_t)b * (NDISP * NDISP) * Hn * Wn;

    // rows r = h + 2dy - 20 for h in {h0, h0+2}: r in [h0-20, h0+22], parity pi
    int rlo = h0 - 20; if (rlo < 0) rlo = pi;
    int rhi = h0 + 22; if (rhi > 47) rhi = 46 + pi;
    int NR  = ((rhi - rlo) >> 1) + 1;           // 12..22
    int NH  = (NR + 1) >> 1;
    int s0  = rh ? NH : 0;
    int s1  = rh ? NR : NH;

    // ---- zero invalid-dy planes (rh==0 blocks only; both h's of the tile) ----
    if (rh == 0) {
        f32x4 z = {0.f, 0.f, 0.f, 0.f};
        #pragma unroll
        for (int ii = 0; ii < 2; ++ii) {
            int h = h0 + 2 * ii;
            int dylo = (h < 20) ? ((21 - h) >> 1) : 0;
            int dyhi = min(NDISP, ((67 - h) >> 1) + 1);
            int nz = NDISP - (dyhi - dylo);
            for (int j = tid; j < nz * NDISP * 16; j += 512) {
                int zi  = j / (NDISP * 16);
                int rem = j - zi * (NDISP * 16);
                int dy  = (zi < dylo) ? zi : (dyhi + (zi - dylo));
                int dx  = rem >> 4;
                int wq  = rem & 15;
                *(f32x4*)&outb[((size_t)(dy * NDISP + dx) * Hn + h) * Wn + wq * 4] = z;
            }
        }
    }

    // ---- A-fragments (VERIFIED contract): af[k8] elem j =
    //      f16(in1[c=k8*32+g*8+j][h_i][w=2*(half*16+nl)+p2]) ----
    f16x8 af[8];
    {
        const int w2 = 2 * (half * 16 + nl);
        #pragma unroll
        for (int k8 = 0; k8 < 8; ++k8)
            #pragma unroll
            for (int j = 0; j < 8; ++j) {
                int c = k8 * 32 + g * 8 + j;
                f32x2 v = *(const f32x2*)&in1b[((size_t)c * Hn + h_i) * Wn + w2];
                af[k8][j] = (f16)(p2 ? v.y : v.x);
            }
    }

    // ---- zero bounce planes ----
    for (int j = tid; j < 2 * 1344; j += 512) (&bounce[0][0])[j] = 0.f;

    const int soff = wv * 4096;                 // this wave's 4KB staging share
    const int l16  = l * 16;

    // ---- prologue: stage row s0 into slot s0&1 ----
    {
        const char* slab = wsb + (size_t)(rlo + 2 * s0) * SLAB;
        char* dst = &ring[s0 & 1][0];
        #pragma unroll
        for (int q = 0; q < 4; ++q) {
            int off = soff + q * 1024 + l16;
            __builtin_amdgcn_global_load_lds((const AS1q void*)(slab + off),
                                             (AS3q void*)(dst + off), 16, 0, 0);
        }
    }

    for (int s = s0; s < s1; ++s) {
        // stage row s+1 (clamped dummy at tail; target slot never read then)
        {
            int sn = (s + 1 < s1) ? s + 1 : s1 - 1;
            const char* slab = wsb + (size_t)(rlo + 2 * sn) * SLAB;
            char* dst = &ring[(s + 1) & 1][0];
            #pragma unroll
            for (int q = 0; q < 4; ++q) {
                int off = soff + q * 1024 + l16;
                __builtin_amdgcn_global_load_lds((const AS1q void*)(slab + off),
                                                 (AS3q void*)(dst + off), 16, 0, 0);
            }
        }
        // barrier1: own stage(s) proven done (4 newer loads in flight; loads
        // retire in order, stores only inflate); bounce zeros/re-zeros visible.
        __builtin_amdgcn_sched_barrier(0);
        asm volatile("s_waitcnt vmcnt(4) lgkmcnt(0)" ::: "memory");
        __builtin_amdgcn_s_barrier();
        __builtin_amdgcn_sched_barrier(0);

        const int r  = rlo + 2 * s;
        const int dy = (r - h_i + 20) / 2;      // exact (even numerator)
        const bool valid = (dy >= 0) && (dy < NDISP);

        if (valid) {
            f32x4 acc[2];                       // [ni]
            acc[0] = acc[1] = (f32x4){0.f, 0.f, 0.f, 0.f};
            const char* base = &ring[s & 1][0] + p2 * 4096;
            #pragma unroll
            for (int k8 = 0; k8 < 8; ++k8) {
                const char* kb = base + (k8 >> 1) * 8192 + (k8 & 1) * 1024 + l16;
                f16x8 b0 = *(const f16x8*)(kb);           // ni = 0
                f16x8 b1 = *(const f16x8*)(kb + 2048);    // ni = 1
                acc[0] = __builtin_amdgcn_mfma_f32_16x16x32_f16(af[k8], b0, acc[0], 0, 0, 0);
                acc[1] = __builtin_amdgcn_mfma_f32_16x16x32_f16(af[k8], b1, acc[1], 0, 0, 0);
            }
            // scatter (VERIFIED o = n - m): n = ni*16+nl, m = half*16+4g+rr,
            // w = 2m+p2, swizzle w ^ ((dx&7)<<3)
            #pragma unroll
            for (int ni = 0; ni < 2; ++ni)
                #pragma unroll
                for (int rr2 = 0; rr2 < 4; ++rr2) {
                    int o = nl + 16 * ni - 16 * half - 4 * g - rr2;  // dx - 10
                    if (o >= -10 && o <= 10) {
                        int dx = o + 10;
                        int m  = half * 16 + 4 * g + rr2;
                        int w  = 2 * m + p2;
                        bounce[i][dx * 64 + (w ^ ((dx & 7) << 3))] = acc[ni][rr2];
                    }
                }
        }
        // barrier2: scatter visible to plane partners; ds_reads retired ->
        // ring slot s&1 free for stage(s+2).
        __builtin_amdgcn_sched_barrier(0);
        asm volatile("s_waitcnt lgkmcnt(0)" ::: "memory");
        __builtin_amdgcn_s_barrier();
        __builtin_amdgcn_sched_barrier(0);

        if (valid) {
            // gather + coalesced f32x4 stores + re-zero (336 = 21 dx x 16 quads
            // per plane; 4 waves of this plane cooperate)
            #pragma unroll
            for (int it = 0; it < 2; ++it) {
                int pos = it * 256 + (wv & 3) * 64 + l;
                if (pos < 336) {
                    int dx = pos >> 4;
                    int q  = pos & 15;
                    int idx = dx * 64 + ((4 * q) ^ ((dx & 7) << 3));
                    f32x4 v = *(f32x4*)&bounce[i][idx];
                    v = v * (1.0f / 256.0f);
                    *(f32x4*)&outb[((size_t)(dy * NDISP + dx) * Hn + h_i) * Wn + 4 * q] = v;
                    *(f32x4*)&bounce[i][idx] = (f32x4){0.f, 0.f, 0.f, 0.f};
                }
            }
        }
    }
}

// ============================================================================
// Fallback (round-1 kernel, known-good) if ws_size is too small.
// ============================================================================
#define BDIM 384
#define C2T  8
#define NCHUNK 16
#define JJN  56
#define IN1_DW (2*128*32)
#define IN2_DW (128*JJN + 64)

__device__ __forceinline__ unsigned int packh2(float a, float b) {
    union { f16x2 h; unsigned int u; } u;
    u.h.x = (_Float16)a; u.h.y = (_Float16)b;
    return u.u;
}
__device__ __forceinline__ float dot2(unsigned int a, unsigned int b, float c) {
    union { unsigned int u; f16x2 h; } ua, ub;
    ua.u = a; ub.u = b;
#if HAVE_FDOT2
    return __builtin_amdgcn_fdot2(ua.h, ub.h, c, false);
#else
    return c + (float)ua.h.x * (float)ub.h.x + (float)ua.h.y * (float)ub.h.y;
#endif
}
__device__ __forceinline__ int in2row(int m) { return m * JJN + (((m >> 3) & 1) << 2); }

__global__ __launch_bounds__(BDIM, 3) void corr_fallback(
    const float* __restrict__ in1, const float* __restrict__ in2,
    float* __restrict__ out)
{
    __shared__ __align__(16) unsigned int s_in1[IN1_DW];
    __shared__ __align__(16) unsigned int s_in2[IN2_DW];
    const int tid = threadIdx.x;
    int bid = blockIdx.x;
    int sw  = (bid & 7) * 96 + (bid >> 3);
    const int b = sw / Hn;
    const int h = sw - b * Hn;
    int dylo = (h < 20) ? ((21 - h) >> 1) : 0;
    int dyhi = min(NDISP - 1, (67 - h) >> 1) + 1;
    const int V = dyhi - dylo;
    const int wg   = tid & 15;
    const int p    = wg & 1;
    const int widx = (wg >> 1) << 2;
    const int t2   = tid >> 4;
    const int dxg  = t2 % 3;
    const int slot = t2 / 3;
    const int dxb  = dxg << 3;
    const float* in1b = in1 + (size_t)b * Cn * Hn * Wn;
    const float* in2b = in2 + (size_t)b * Cn * Hn * Wn;
    float* outb = out + (size_t)b * (NDISP * NDISP) * Hn * Wn;
    {
        int nz = NDISP - V;
        for (int j = tid; j < nz * NDISP * Wn; j += BDIM) {
            int zi  = j / (NDISP * Wn);
            int rem = j - zi * (NDISP * Wn);
            int dy  = (zi < dylo) ? zi : (dyhi + (zi - dylo));
            int dx  = rem >> 6;
            int w   = rem & 63;
            outb[((size_t)(dy * NDISP + dx) * Hn + h) * Wn + w] = 0.0f;
        }
    }
    for (int i = tid; i < 64 * 128; i += BDIM) {
        int w  = i & 63;
        int c2 = i >> 6;
        float f0 = in1b[((size_t)(2 * c2)     * Hn + h) * Wn + w];
        float f1 = in1b[((size_t)(2 * c2 + 1) * Hn + h) * Wn + w];
        int pp = w & 1, wq = w >> 1;
        s_in1[(pp * 128 + c2) * 32 + wq] = packh2(f0, f1);
    }
    const int nR = (V + 7) >> 3;
    for (int round = 0; round < nR; ++round) {
        const int dy0   = dylo + (round << 3);
        const int mydy  = dy0 + slot;
        const bool valid = (mydy < dyhi);
        float acc[4][8];
        #pragma unroll
        for (int i = 0; i < 4; ++i)
            #pragma unroll
            for (int j = 0; j < 8; ++j) acc[i][j] = 0.0f;
        for (int ch = 0; ch < NCHUNK; ++ch) {
            const int c2b = ch * C2T;
            __syncthreads();
            for (int i = tid; i < 8 * 2 * C2T * 112 / 2; i += BDIM) {
                int jj2 = i % 112;
                int t   = i / 112;
                int pp  = jj2 & 1;
                int jj  = jj2 >> 1;
                int c2o = t % C2T;
                int sl  = t / C2T;
                int dy  = dy0 + sl;
                if (dy >= dyhi) continue;
                int w2  = jj2 - 20;
                unsigned int val = 0;
                if (w2 >= 0 && w2 < Wn) {
                    int rr = h + 2 * dy - 20;
                    int c = 2 * (c2b + c2o);
                    const float* srcp = &in2b[((size_t)c * Hn + rr) * Wn + w2];
                    val = packh2(srcp[0], srcp[Hn * Wn]);
                }
                s_in2[in2row((sl * 2 + pp) * C2T + c2o) + jj] = val;
            }
            __syncthreads();
            if (valid) {
                const int base1 = (p * 128 + c2b) * 32 + widx;
                #pragma unroll
                for (int c2o = 0; c2o < C2T; ++c2o) {
                    u32x4 a4 = *(const u32x4*)&s_in1[base1 + c2o * 32];
                    const unsigned int* vr =
                        &s_in2[in2row((slot * 2 + p) * C2T + c2o) + widx + dxb];
                    u32x4 v0 = *(const u32x4*)(vr);
                    u32x4 v1 = *(const u32x4*)(vr + 4);
                    u32x4 v2 = *(const u32x4*)(vr + 8);
                    unsigned int av[4]  = {a4.x, a4.y, a4.z, a4.w};
                    unsigned int vv[12] = {v0.x, v0.y, v0.z, v0.w,
                                           v1.x, v1.y, v1.z, v1.w,
                                           v2.x, v2.y, v2.z, v2.w};
                    #pragma unroll
                    for (int wi = 0; wi < 4; ++wi)
                        #pragma unroll
                        for (int di = 0; di < 8; ++di)
                            acc[wi][di] = dot2(av[wi], vv[wi + di], acc[wi][di]);
                }
            }
        }
        float* s_out = (float*)s_in2;
        for (int half = 0; half < 2; ++half) {
            __syncthreads();
            if (((slot >> 2) == half) && valid) {
                #pragma unroll
                for (int wi = 0; wi < 4; ++wi)
                    #pragma unroll
                    for (int di = 0; di < 8; ++di) {
                        int dx = dxb + di;
                        if (dx < NDISP) {
                            int w = p + ((widx + wi) << 1);
                            s_out[(((slot & 3) * NDISP + dx) << 6) + w] =
                                acc[wi][di] * (1.0f / 256.0f);
                        }
                    }
            }
            __syncthreads();
            int dyb = dy0 + (half << 2);
            for (int j = tid; j < 4 * NDISP * Wn; j += BDIM) {
                int s  = j / (NDISP * Wn);
                int dy = dyb + s;
                if (dy < dyhi) {
                    int rem = j - s * (NDISP * Wn);
                    int dx  = rem >> 6;
                    int w   = rem & 63;
                    outb[((size_t)(dy * NDISP + dx) * Hn + h) * Wn + w] = s_out[j];
                }
            }
        }
    }
}

extern "C" void kernel_launch(void* const* d_in, const int* in_sizes, int n_in,
                              void* d_out, int out_size, void* d_ws, size_t ws_size,
                              hipStream_t stream) {
    (void)in_sizes; (void)n_in; (void)out_size;
    const float* in1 = (const float*)d_in[0];
    const float* in2 = (const float*)d_in[1];
    float* out = (float*)d_out;
    if (ws_size >= WS_NEED) {
        convert_kernel<<<dim3(Bn * Hn), dim3(256), 0, stream>>>(in2, (char*)d_ws);
        corr_mfma<<<dim3(768), dim3(512), 0, stream>>>(in1, (const char*)d_ws, out);
    } else {
        corr_fallback<<<dim3(Bn * Hn), dim3(BDIM), 0, stream>>>(in1, in2, out);
    }
}

// Round 16
// 64.324 us; speedup vs baseline: 1.6797x; 1.0338x over previous
//
#include <hip/hip_runtime.h>

#ifndef __has_builtin
#define __has_builtin(x) 0
#endif
#if __has_builtin(__builtin_amdgcn_fdot2)
#define HAVE_FDOT2 1
#else
#define HAVE_FDOT2 0
#endif

#define AS1q __attribute__((address_space(1)))
#define AS3q __attribute__((address_space(3)))

typedef _Float16 f16;
typedef _Float16 f16x2 __attribute__((ext_vector_type(2)));
typedef _Float16 f16x8 __attribute__((ext_vector_type(8)));
typedef float    f32x4 __attribute__((ext_vector_type(4)));
typedef float    f32x2 __attribute__((ext_vector_type(2)));
typedef unsigned int u32x4 __attribute__((ext_vector_type(4)));

#define Bn 16
#define Cn 256
#define Hn 48
#define Wn 64
#define NDISP 21
#define SLAB 32768                      // bytes per (b,row) slab of in2, f16
#define WS_NEED ((size_t)Bn * Hn * SLAB)   // 25.2 MB

// ============================================================================
// Conversion kernel (in2 only), VERIFIED layout R5-R15, with XCD-ALIGNED
// block mapping (new in V16): xcd = bid&7 owns b in {2*xcd, 2*xcd+1}, matching
// the main kernel's b-affinity, so each ws[b] slice is write-allocated into
// the SAME XCD L2 that main will read it from (3.15 MB/XCD, L2-fit).
//   slab(b,row) offset = kc*8192 + par*4096 + ni*2048 + kk*1024 + g*256 + nl*16 + j*2
//   holds in2[b][c = kc*64 + kk*32 + g*8 + j][row][w = 2*(ni*16+nl) + par]
// ============================================================================
__global__ __launch_bounds__(256) void convert_kernel(const float* __restrict__ in2,
                                                      char* __restrict__ ws)
{
    int bid = blockIdx.x;                       // 0..767
    int j   = bid >> 3;                         // 0..95
    int b   = 2 * (bid & 7) + (j >= Hn ? 1 : 0);
    int row = (j >= Hn) ? (j - Hn) : j;
    char* dslab = ws + (size_t)(b * Hn + row) * SLAB;
    int t  = threadIdx.x;
    int nl = t & 15, g = (t >> 4) & 3, kk = (t >> 6) & 1, ni = (t >> 7) & 1;
    int wq = ni * 16 + nl;                      // w' 0..31
    const float* srcb = in2 + ((size_t)b * Cn * Hn + row) * Wn;
    char* dbase = dslab + ni * 2048 + kk * 1024 + g * 256 + nl * 16;
    #pragma unroll
    for (int kc = 0; kc < 4; ++kc) {
        union { f16 h[8]; u32x4 u; } e0, e1;
        #pragma unroll
        for (int jj = 0; jj < 8; ++jj) {
            int c = kc * 64 + kk * 32 + g * 8 + jj;
            f32x2 v = *(const f32x2*)&srcb[(size_t)c * Hn * Wn + 2 * wq];
            e0.h[jj] = (f16)v.x;                // even w  (par 0)
            e1.h[jj] = (f16)v.y;                // odd  w  (par 1)
        }
        *(u32x4*)(dbase + kc * 8192)        = e0.u;
        *(u32x4*)(dbase + kc * 8192 + 4096) = e1.u;
    }
}

// ============================================================================
// Main kernel = R10's PASSING best (64.9 us total), byte-identical. Block =
// (b, parity pi, 4-h tile): 192 blocks, 512 thr, 8 waves = (plane i x parity).
// Per step: one in2 row slab staged once into a 4-slot LDS ring
// (global_load_lds, depth-3, counted vmcnt(12) + raw s_barrier); per valid
// (h,dy): af[mi][k8] in regs, 16 ds_read_b128 + 16 MFMA, scatter into
// pair-shared XOR-swizzled bounce, coalesced f32x4 stores.
// ============================================================================
__device__ __forceinline__ void stage4(const char* slab, char* slot, int off0, int l16)
{
    #pragma unroll
    for (int q = 0; q < 4; ++q) {
        int off = off0 + q * 1024 + l16;
        __builtin_amdgcn_global_load_lds((const AS1q void*)(slab + off),
                                         (AS3q void*)(slot + off), 16, 0, 0);
    }
}

__global__ __launch_bounds__(512, 2) void corr_mfma(const float* __restrict__ in1,
                                                    const char* __restrict__ ws,
                                                    float* __restrict__ out)
{
    __shared__ char  Bring[4][32768];           // row-slab ring (128 KB)
    __shared__ float bounce[4][1344];           // per-h [21 dx][64 w] planes (21 KB)

    const int tid = threadIdx.x;
    const int wv  = tid >> 6;
    const int l   = tid & 63;
    const int nl  = l & 15;
    const int g   = l >> 4;
    const int i   = wv >> 1;                    // h index 0..3
    const int p2  = wv & 1;                     // w parity

    int bid = blockIdx.x;
    int swz = (bid & 7) * 24 + (bid >> 3);      // 192 = 8*24, bijective XCD swizzle
    int b   = swz / 12;
    int rem = swz - b * 12;
    int pi  = rem / 6;
    int t   = rem - pi * 6;
    int h0  = pi + 8 * t;
    int h   = h0 + 2 * i;

    const float* in1b = in1 + (size_t)b * Cn * Hn * Wn;
    const char*  wsb  = ws  + (size_t)b * Hn * SLAB;
    float* outb = out + (size_t)b * (NDISP * NDISP) * Hn * Wn;

    int rlo = (h0 >= 20) ? (h0 - 20) : pi;      // parity-preserving clip
    int rhi = min(h0 + 26, 46 + pi);
    int NR  = ((rhi - rlo) >> 1) + 1;           // 14..22
    int dybase = (rlo - h0 + 20) >> 1;          // dy(s,i) = s + dybase - i

    // ---- zero invalid-dy planes for this h (dx split by parity wave) ----
    {
        int dylo = (h < 20) ? ((21 - h) >> 1) : 0;
        int dyhi = min(NDISP, ((67 - h) >> 1) + 1);
        f32x4 z = {0.f, 0.f, 0.f, 0.f};
        for (int dy = 0; dy < NDISP; ++dy) {
            if (dy >= dylo && dy < dyhi) continue;
            #pragma unroll
            for (int q = 0; q < 3; ++q) {
                int dx = p2 * 12 + q * 4 + g;
                if (dx < NDISP)
                    *(f32x4*)&outb[((size_t)(dy * NDISP + dx) * Hn + h) * Wn + nl * 4] = z;
            }
        }
    }

    // ---- A preload (VERIFIED frag contract): af[mi][k8] elem j =
    //      f16(in1[c=k8*32+g*8+j][h][w=2*(mi*16+nl)+p2]) ----
    f16x8 af[2][8];
    #pragma unroll
    for (int mi = 0; mi < 2; ++mi) {
        int wcol = 2 * (mi * 16 + nl) + p2;
        #pragma unroll
        for (int k8 = 0; k8 < 8; ++k8)
            #pragma unroll
            for (int jj = 0; jj < 8; ++jj) {
                int c = k8 * 32 + g * 8 + jj;
                af[mi][k8][jj] = (f16)in1b[((size_t)c * Hn + h) * Wn + wcol];
            }
    }

    // ---- zero bounce planes ----
    {
        f32x4* bz = (f32x4*)&bounce[0][0];
        #pragma unroll
        for (int q = 0; q < 3; ++q) {
            int idx = q * 512 + tid;
            if (idx < 4 * 1344 / 4) bz[idx] = (f32x4){0.f, 0.f, 0.f, 0.f};
        }
    }

    asm volatile("s_waitcnt vmcnt(0)" ::: "memory");   // A-loads done; vmem queue known

    const int off0 = wv * 4096;                 // this wave's 4 KB staging share
    const int l16  = l * 16;

    // ---- prologue: stage rows 0..2 into slots 0..2 ----
    #pragma unroll
    for (int ps = 0; ps < 3; ++ps)
        stage4(wsb + (size_t)(rlo + 2 * min(ps, NR - 1)) * SLAB, &Bring[ps][0], off0, l16);

    for (int s = 0; s < NR; ++s) {
        // phase A: stage row s+3 (clamped dummy at tail keeps vmcnt uniform)
        stage4(wsb + (size_t)(rlo + 2 * min(s + 3, NR - 1)) * SLAB,
               &Bring[(s + 3) & 3][0], off0, l16);
        // barrier1: counted vmcnt keeps the DMA queue ALIVE across the barrier
        __builtin_amdgcn_sched_barrier(0);
        asm volatile("s_waitcnt vmcnt(12) lgkmcnt(0)" ::: "memory");
        __builtin_amdgcn_s_barrier();
        __builtin_amdgcn_sched_barrier(0);

        int dy = s + dybase - i;
        bool valid = (unsigned)dy < (unsigned)NDISP;
        const char* slot = &Bring[s & 3][0];
        float* bp = &bounce[i][0];

        if (valid) {
            f32x4 acc[2][2];                    // [mi][ni]
            acc[0][0] = acc[0][1] = acc[1][0] = acc[1][1] = (f32x4){0.f, 0.f, 0.f, 0.f};
            #pragma unroll
            for (int k8 = 0; k8 < 8; ++k8) {
                const char* kb = slot + (k8 >> 1) * 8192 + (k8 & 1) * 1024 + p2 * 4096;
                f16x8 b0 = *(const f16x8*)(kb + l16);
                f16x8 b1 = *(const f16x8*)(kb + 2048 + l16);
                #pragma unroll
                for (int mi = 0; mi < 2; ++mi) {
                    acc[mi][0] = __builtin_amdgcn_mfma_f32_16x16x32_f16(af[mi][k8], b0, acc[mi][0], 0, 0, 0);
                    acc[mi][1] = __builtin_amdgcn_mfma_f32_16x16x32_f16(af[mi][k8], b1, acc[mi][1], 0, 0, 0);
                }
            }
            // scatter diag band into pair-shared bounce (w XOR-swizzled per dx)
            #pragma unroll
            for (int mi = 0; mi < 2; ++mi)
                #pragma unroll
                for (int ni = 0; ni < 2; ++ni)
                    #pragma unroll
                    for (int rr = 0; rr < 4; ++rr) {
                        int o = nl + ((ni - mi) << 4) - 4 * g - rr;   // dx - 10
                        if (o >= -10 && o <= 10) {
                            int m  = mi * 16 + 4 * g + rr;
                            int dx = o + 10;
                            int wsw = (2 * m + p2) ^ ((dx & 7) << 3);
                            bp[dx * 64 + wsw] = acc[mi][ni][rr];
                        }
                    }
        }
        // barrier2: LDS-only wait (scatter visible; ds_reads retired -> ring
        // slot free for the next stage); vmem queue untouched.
        __builtin_amdgcn_sched_barrier(0);
        asm volatile("s_waitcnt lgkmcnt(0)" ::: "memory");
        __builtin_amdgcn_s_barrier();
        __builtin_amdgcn_sched_barrier(0);

        if (valid) {
            #pragma unroll
            for (int q = 0; q < 3; ++q) {
                int dx = p2 * 12 + q * 4 + g;
                if (dx < NDISP) {
                    int wb = (4 * nl) ^ ((dx & 7) << 3);
                    f32x4 v = *(f32x4*)&bp[dx * 64 + wb];
                    v = v * (1.0f / 256.0f);
                    *(f32x4*)&outb[((size_t)(dy * NDISP + dx) * Hn + h) * Wn + nl * 4] = v;
                    *(f32x4*)&bp[dx * 64 + wb] = (f32x4){0.f, 0.f, 0.f, 0.f};  // re-zero
                }
            }
        }
    }
}

// ============================================================================
// Fallback (round-1 kernel, known-good) if ws_size is too small.
// ============================================================================
#define BDIM 384
#define C2T  8
#define NCHUNK 16
#define JJN  56
#define IN1_DW (2*128*32)
#define IN2_DW (128*JJN + 64)

__device__ __forceinline__ unsigned int packh2(float a, float b) {
    union { f16x2 h; unsigned int u; } u;
    u.h.x = (_Float16)a; u.h.y = (_Float16)b;
    return u.u;
}
__device__ __forceinline__ float dot2(unsigned int a, unsigned int b, float c) {
    union { unsigned int u; f16x2 h; } ua, ub;
    ua.u = a; ub.u = b;
#if HAVE_FDOT2
    return __builtin_amdgcn_fdot2(ua.h, ub.h, c, false);
#else
    return c + (float)ua.h.x * (float)ub.h.x + (float)ua.h.y * (float)ub.h.y;
#endif
}
__device__ __forceinline__ int in2row(int m) { return m * JJN + (((m >> 3) & 1) << 2); }

__global__ __launch_bounds__(BDIM, 3) void corr_fallback(
    const float* __restrict__ in1, const float* __restrict__ in2,
    float* __restrict__ out)
{
    __shared__ __align__(16) unsigned int s_in1[IN1_DW];
    __shared__ __align__(16) unsigned int s_in2[IN2_DW];
    const int tid = threadIdx.x;
    int bid = blockIdx.x;
    int sw  = (bid & 7) * 96 + (bid >> 3);
    const int b = sw / Hn;
    const int h = sw - b * Hn;
    int dylo = (h < 20) ? ((21 - h) >> 1) : 0;
    int dyhi = min(NDISP - 1, (67 - h) >> 1) + 1;
    const int V = dyhi - dylo;
    const int wg   = tid & 15;
    const int p    = wg & 1;
    const int widx = (wg >> 1) << 2;
    const int t2   = tid >> 4;
    const int dxg  = t2 % 3;
    const int slot = t2 / 3;
    const int dxb  = dxg << 3;
    const float* in1b = in1 + (size_t)b * Cn * Hn * Wn;
    const float* in2b = in2 + (size_t)b * Cn * Hn * Wn;
    float* outb = out + (size_t)b * (NDISP * NDISP) * Hn * Wn;
    {
        int nz = NDISP - V;
        for (int j = tid; j < nz * NDISP * Wn; j += BDIM) {
            int zi  = j / (NDISP * Wn);
            int rem = j - zi * (NDISP * Wn);
            int dy  = (zi < dylo) ? zi : (dyhi + (zi - dylo));
            int dx  = rem >> 6;
            int w   = rem & 63;
            outb[((size_t)(dy * NDISP + dx) * Hn + h) * Wn + w] = 0.0f;
        }
    }
    for (int i = tid; i < 64 * 128; i += BDIM) {
        int w  = i & 63;
        int c2 = i >> 6;
        float f0 = in1b[((size_t)(2 * c2)     * Hn + h) * Wn + w];
        float f1 = in1b[((size_t)(2 * c2 + 1) * Hn + h) * Wn + w];
        int pp = w & 1, wq = w >> 1;
        s_in1[(pp * 128 + c2) * 32 + wq] = packh2(f0, f1);
    }
    const int nR = (V + 7) >> 3;
    for (int round = 0; round < nR; ++round) {
        const int dy0   = dylo + (round << 3);
        const int mydy  = dy0 + slot;
        const bool valid = (mydy < dyhi);
        float acc[4][8];
        #pragma unroll
        for (int i = 0; i < 4; ++i)
            #pragma unroll
            for (int j = 0; j < 8; ++j) acc[i][j] = 0.0f;
        for (int ch = 0; ch < NCHUNK; ++ch) {
            const int c2b = ch * C2T;
            __syncthreads();
            for (int i = tid; i < 8 * 2 * C2T * 112 / 2; i += BDIM) {
                int jj2 = i % 112;
                int t   = i / 112;
                int pp  = jj2 & 1;
                int jj  = jj2 >> 1;
                int c2o = t % C2T;
                int sl  = t / C2T;
                int dy  = dy0 + sl;
                if (dy >= dyhi) continue;
                int w2  = jj2 - 20;
                unsigned int val = 0;
                if (w2 >= 0 && w2 < Wn) {
                    int rr = h + 2 * dy - 20;
                    int c = 2 * (c2b + c2o);
                    const float* srcp = &in2b[((size_t)c * Hn + rr) * Wn + w2];
                    val = packh2(srcp[0], srcp[Hn * Wn]);
                }
                s_in2[in2row((sl * 2 + pp) * C2T + c2o) + jj] = val;
            }
            __syncthreads();
            if (valid) {
                const int base1 = (p * 128 + c2b) * 32 + widx;
                #pragma unroll
                for (int c2o = 0; c2o < C2T; ++c2o) {
                    u32x4 a4 = *(const u32x4*)&s_in1[base1 + c2o * 32];
                    const unsigned int* vr =
                        &s_in2[in2row((slot * 2 + p) * C2T + c2o) + widx + dxb];
                    u32x4 v0 = *(const u32x4*)(vr);
                    u32x4 v1 = *(const u32x4*)(vr + 4);
                    u32x4 v2 = *(const u32x4*)(vr + 8);
                    unsigned int av[4]  = {a4.x, a4.y, a4.z, a4.w};
                    unsigned int vv[12] = {v0.x, v0.y, v0.z, v0.w,
                                           v1.x, v1.y, v1.z, v1.w,
                                           v2.x, v2.y, v2.z, v2.w};
                    #pragma unroll
                    for (int wi = 0; wi < 4; ++wi)
                        #pragma unroll
                        for (int di = 0; di < 8; ++di)
                            acc[wi][di] = dot2(av[wi], vv[wi + di], acc[wi][di]);
                }
            }
        }
        float* s_out = (float*)s_in2;
        for (int half = 0; half < 2; ++half) {
            __syncthreads();
            if (((slot >> 2) == half) && valid) {
                #pragma unroll
                for (int wi = 0; wi < 4; ++wi)
                    #pragma unroll
                    for (int di = 0; di < 8; ++di) {
                        int dx = dxb + di;
                        if (dx < NDISP) {
                            int w = p + ((widx + wi) << 1);
                            s_out[(((slot & 3) * NDISP + dx) << 6) + w] =
                                acc[wi][di] * (1.0f / 256.0f);
                        }
                    }
            }
            __syncthreads();
            int dyb = dy0 + (half << 2);
            for (int j = tid; j < 4 * NDISP * Wn; j += BDIM) {
                int s  = j / (NDISP * Wn);
                int dy = dyb + s;
                if (dy < dyhi) {
                    int rem = j - s * (NDISP * Wn);
                    int dx  = rem >> 6;
                    int w   = rem & 63;
                    outb[((size_t)(dy * NDISP + dx) * Hn + h) * Wn + w] = s_out[j];
                }
            }
        }
    }
}

extern "C" void kernel_launch(void* const* d_in, const int* in_sizes, int n_in,
                              void* d_out, int out_size, void* d_ws, size_t ws_size,
                              hipStream_t stream) {
    (void)in_sizes; (void)n_in; (void)out_size;
    const float* in1 = (const float*)d_in[0];
    const float* in2 = (const float*)d_in[1];
    float* out = (float*)d_out;
    if (ws_size >= WS_NEED) {
        convert_kernel<<<dim3(Bn * Hn), dim3(256), 0, stream>>>(in2, (char*)d_ws);
        corr_mfma<<<dim3(192), dim3(512), 0, stream>>>(in1, (const char*)d_ws, out);
    } else {
        corr_fallback<<<dim3(Bn * Hn), dim3(BDIM), 0, stream>>>(in1, in2, out);
    }
}